// Round 8
// baseline (1238.778 us; speedup 1.0000x reference)
//
#include <hip/hip_runtime.h>
#include <hip/hip_bf16.h>
#include <math.h>

// N=1e6 nodes, D_IN=128, hidden=64, D_OUT=128, SEGS=8192.
#define D   128
#define DH  64

typedef __attribute__((ext_vector_type(8))) __bf16 bf16x8;
typedef __attribute__((ext_vector_type(4))) float  f32x4;

union BF4 { __bf16 b[4]; ushort4 u; };

// split v -> hi + lo (both bf16): hi = rne(v), lo = rne(v - hi)
static __device__ __forceinline__ void bf16_split(float v, __bf16& hi, __bf16& lo) {
    hi = (__bf16)v;
    lo = (__bf16)(v - (float)hi);
}

// ---------- K0: zero denom + transpose/split weights ----------
__global__ void init_kernel(const float* __restrict__ Wt, const float* __restrict__ W1,
                            float* __restrict__ denom,
                            __bf16* __restrict__ WtT_hi, __bf16* __restrict__ WtT_lo,
                            __bf16* __restrict__ W1T_hi,
                            int nseg) {
    int i = blockIdx.x * 256 + threadIdx.x;
    if (i < nseg) denom[i] = 0.0f;
    if (i < D * D) {                      // WtT[j][k] = Wt[k][j]
        int j = i >> 7, k = i & (D - 1);
        __bf16 hi, lo; bf16_split(Wt[k * D + j], hi, lo);
        WtT_hi[j * D + k] = hi; WtT_lo[j * D + k] = lo;
    }
    if (i < DH * D) {                     // W1T[h][k] = W1[k][h]  (hi only: gate is 2-term)
        int h = i >> 7, k = i & (D - 1);
        W1T_hi[h * D + k] = (__bf16)W1[k * DH + h];
    }
}

// write a staged fp32 chunk (8 float4 regs/thread) as swizzled hi/lo bf16 planes
static __device__ __forceinline__ void write_x_planes(
        const float4* xv, int tid, unsigned char* Ahi, unsigned char* Alo) {
    #pragma unroll
    for (int q = 0; q < 8; ++q) {
        int f = q * 256 + tid;            // float4 id within chunk (2048 total)
        int row = f >> 5, c4 = f & 31;
        BF4 h4, l4;
        bf16_split(xv[q].x, h4.b[0], l4.b[0]);
        bf16_split(xv[q].y, h4.b[1], l4.b[1]);
        bf16_split(xv[q].z, h4.b[2], l4.b[2]);
        bf16_split(xv[q].w, h4.b[3], l4.b[3]);
        int byte = (row * 256 + c4 * 8) ^ ((row & 7) << 4);
        *(ushort4*)(Ahi + byte) = h4.u;
        *(ushort4*)(Alo + byte) = l4.u;
    }
}

static __device__ __forceinline__ void load_x_chunk(
        const float4* __restrict__ xs, int chunk, int n_nodes, int tid, float4* xv) {
    #pragma unroll
    for (int q = 0; q < 8; ++q) {
        int f = q * 256 + tid;
        int node = chunk * 64 + (f >> 5);
        xv[q] = (node < n_nodes) ? xs[(size_t)chunk * 2048 + f]
                                 : make_float4(0.f, 0.f, 0.f, 0.f);
    }
}

// ---------- K1 (fused): gate -> e=exp(gate); denom += e; out += e * relu(x@Wt+bt) ----------
// x staged to LDS once per chunk; merged GEMM loop (one A-read feeds gate + transform).
// 2 barriers per chunk. e computed redundantly per wave (no eld buffer / wave0 phase).
__global__ __launch_bounds__(256, 3)
void fused_kernel(const float* __restrict__ x, const int* __restrict__ idx,
                  const __bf16* __restrict__ W1T_hi,
                  const float* __restrict__ b1, const float* __restrict__ W2,
                  const float* __restrict__ b2,
                  const __bf16* __restrict__ WtT_hi, const __bf16* __restrict__ WtT_lo,
                  const float* __restrict__ bt,
                  float* __restrict__ denom, float* __restrict__ out,
                  int n_nodes, int nchunks) {
    __shared__ __align__(16) unsigned char Ahi[64 * 256], Alo[64 * 256];  // 32 KB
    __shared__ float gpart[4][64];
    __shared__ int   segs[2][64];
    int tid = threadIdx.x, lane = tid & 63, w = tid >> 6;
    int g = lane >> 4, l15 = lane & 15;

    // gate B frags (hi only): wave w owns hidden cols w*16..w*16+15 (16 VGPR)
    bf16x8 B1h[4];
    {
        const __bf16* ph = W1T_hi + (size_t)(w * 16 + l15) * D;
        #pragma unroll
        for (int kk = 0; kk < 4; ++kk)
            B1h[kk] = *(const bf16x8*)(ph + kk * 32 + g * 8);
    }
    // transform B frags: wave w owns out cols (2w..2w+1)*16 (64 VGPR)
    bf16x8 Bth[2][4], Btl[2][4];
    #pragma unroll
    for (int nt = 0; nt < 2; ++nt) {
        const __bf16* ph = WtT_hi + (size_t)((2 * w + nt) * 16 + l15) * D;
        const __bf16* pl = WtT_lo + (size_t)((2 * w + nt) * 16 + l15) * D;
        #pragma unroll
        for (int kk = 0; kk < 4; ++kk) {
            Bth[nt][kk] = *(const bf16x8*)(ph + kk * 32 + g * 8);
            Btl[nt][kk] = *(const bf16x8*)(pl + kk * 32 + g * 8);
        }
    }
    float b1v = b1[w * 16 + l15], w2v = W2[w * 16 + l15], b2v = b2[0];
    float btv[2] = { bt[(2 * w + 0) * 16 + l15], bt[(2 * w + 1) * 16 + l15] };
    const float4* xs = (const float4*)x;

    // prologue: stage chunk c0 (A + segs[0])
    {
        int c0 = blockIdx.x;
        if (c0 < nchunks) {
            float4 xv[8];
            load_x_chunk(xs, c0, n_nodes, tid, xv);
            write_x_planes(xv, tid, Ahi, Alo);
            if (tid < 64) {
                int node = c0 * 64 + tid;
                segs[0][tid] = (node < n_nodes) ? idx[node] : 0;
            }
        }
    }

    int p = 0;
    for (int c = blockIdx.x; c < nchunks; c += gridDim.x, p ^= 1) {
        __syncthreads();                        // A(c) + segs[p] staged & visible
        int cn = c + gridDim.x;
        float4 xn[8]; int sgn = 0;
        if (cn < nchunks) {
            load_x_chunk(xs, cn, n_nodes, tid, xn);        // prefetch: issue early
            if (tid < 64) {
                int node = cn * 64 + tid;
                sgn = (node < n_nodes) ? idx[node] : 0;
            }
        }

        // ---- merged GEMM: one A-fragment read feeds gate (2 MFMA) + transform (6 MFMA) ----
        f32x4 gacc[4];
        f32x4 acc[4][2];
        #pragma unroll
        for (int rt = 0; rt < 4; ++rt) {
            gacc[rt] = (f32x4){0.f, 0.f, 0.f, 0.f};
            #pragma unroll
            for (int nt = 0; nt < 2; ++nt) acc[rt][nt] = (f32x4){0.f, 0.f, 0.f, 0.f};
        }
        #pragma unroll
        for (int kk = 0; kk < 4; ++kk) {
            #pragma unroll
            for (int rt = 0; rt < 4; ++rt) {
                int arow = rt * 16 + l15;
                int ab = (arow * 256 + kk * 64 + g * 16) ^ ((arow & 7) << 4);
                bf16x8 ah = *(const bf16x8*)(Ahi + ab);
                bf16x8 al = *(const bf16x8*)(Alo + ab);
                gacc[rt] = __builtin_amdgcn_mfma_f32_16x16x32_bf16(ah, B1h[kk], gacc[rt], 0, 0, 0);
                gacc[rt] = __builtin_amdgcn_mfma_f32_16x16x32_bf16(al, B1h[kk], gacc[rt], 0, 0, 0);
                #pragma unroll
                for (int nt = 0; nt < 2; ++nt) {
                    acc[rt][nt] = __builtin_amdgcn_mfma_f32_16x16x32_bf16(ah, Bth[nt][kk], acc[rt][nt], 0, 0, 0);
                    acc[rt][nt] = __builtin_amdgcn_mfma_f32_16x16x32_bf16(ah, Btl[nt][kk], acc[rt][nt], 0, 0, 0);
                    acc[rt][nt] = __builtin_amdgcn_mfma_f32_16x16x32_bf16(al, Bth[nt][kk], acc[rt][nt], 0, 0, 0);
                }
            }
        }

        // ---- gate partial reduce over this wave's 16 hidden cols ----
        #pragma unroll
        for (int rt = 0; rt < 4; ++rt) {
            #pragma unroll
            for (int r = 0; r < 4; ++r) {
                float pv = fmaxf(gacc[rt][r] + b1v, 0.f) * w2v;
                pv += __shfl_xor(pv, 1);
                pv += __shfl_xor(pv, 2);
                pv += __shfl_xor(pv, 4);
                pv += __shfl_xor(pv, 8);
                if (l15 == 0) gpart[w][rt * 16 + g * 4 + r] = pv;
            }
        }
        __syncthreads();                        // gpart ready; all A reads done

        // ---- e per lane (every wave, redundant — no extra barrier) ----
        float gt = gpart[0][lane] + gpart[1][lane] + gpart[2][lane] + gpart[3][lane] + b2v;
        int node0 = c * 64 + lane;
        float e = (node0 < n_nodes) ? __expf(gt) : 0.f;

        // ---- wave0: denom atomics (concurrent with other waves' epilogues) ----
        if (w == 0) {
            int ga = lane >> 4;
            int sa = segs[p][ga * 16], sb = segs[p][ga * 16 + 15];
            if (sa == sb) {
                float v = e;
                v += __shfl_xor(v, 1);
                v += __shfl_xor(v, 2);
                v += __shfl_xor(v, 4);
                v += __shfl_xor(v, 8);
                if ((lane & 15) == 0) atomicAdd(denom + sa, v);
            } else {
                atomicAdd(denom + segs[p][lane], e);
            }
        }

        // ---- scatter epilogue: out += e * relu(t + bt), segmented column sums ----
        int s0 = segs[p][0], s63 = segs[p][63];
        if (s0 == s63) {                        // whole chunk one segment
            float s[2] = {0.f, 0.f};
            #pragma unroll
            for (int rt = 0; rt < 4; ++rt)
                #pragma unroll
                for (int r = 0; r < 4; ++r) {
                    float a = __shfl(e, rt * 16 + g * 4 + r);
                    s[0] += a * fmaxf(acc[rt][0][r] + btv[0], 0.f);
                    s[1] += a * fmaxf(acc[rt][1][r] + btv[1], 0.f);
                }
            s[0] += __shfl_xor(s[0], 16); s[0] += __shfl_xor(s[0], 32);
            s[1] += __shfl_xor(s[1], 16); s[1] += __shfl_xor(s[1], 32);
            if (g == 0)      atomicAdd(&out[(size_t)s0 * D + (2 * w + 0) * 16 + l15], s[0]);
            else if (g == 1) atomicAdd(&out[(size_t)s0 * D + (2 * w + 1) * 16 + l15], s[1]);
        } else {
            #pragma unroll
            for (int rt = 0; rt < 4; ++rt) {
                int sa = segs[p][rt * 16], sb = segs[p][rt * 16 + 15];
                if (sa == sb) {                 // 16-row tile uniform
                    float s[2] = {0.f, 0.f};
                    #pragma unroll
                    for (int r = 0; r < 4; ++r) {
                        float a = __shfl(e, rt * 16 + g * 4 + r);
                        s[0] += a * fmaxf(acc[rt][0][r] + btv[0], 0.f);
                        s[1] += a * fmaxf(acc[rt][1][r] + btv[1], 0.f);
                    }
                    s[0] += __shfl_xor(s[0], 16); s[0] += __shfl_xor(s[0], 32);
                    s[1] += __shfl_xor(s[1], 16); s[1] += __shfl_xor(s[1], 32);
                    if (g == 0)      atomicAdd(&out[(size_t)sa * D + (2 * w + 0) * 16 + l15], s[0]);
                    else if (g == 1) atomicAdd(&out[(size_t)sa * D + (2 * w + 1) * 16 + l15], s[1]);
                } else {                        // boundary inside tile: per-row atomics
                    #pragma unroll
                    for (int r = 0; r < 4; ++r) {
                        int row = rt * 16 + g * 4 + r;
                        int sg = segs[p][row];
                        float a = __shfl(e, row);
                        atomicAdd(&out[(size_t)sg * D + (2 * w + 0) * 16 + l15],
                                  a * fmaxf(acc[rt][0][r] + btv[0], 0.f));
                        atomicAdd(&out[(size_t)sg * D + (2 * w + 1) * 16 + l15],
                                  a * fmaxf(acc[rt][1][r] + btv[1], 0.f));
                    }
                }
            }
        }

        // ---- stage next chunk (A consumed; atomics drain under these LDS writes) ----
        if (cn < nchunks) {
            write_x_planes(xn, tid, Ahi, Alo);
            if (tid < 64) segs[p ^ 1][tid] = sgn;
        }
    }
}

// ---------- K2: out[s][:] /= (denom[s] + eps) ----------
__global__ void norm_kernel(float4* __restrict__ out4, const float* __restrict__ denom,
                            int n4) {
    int i = blockIdx.x * 256 + threadIdx.x;
    if (i >= n4) return;
    float rd = 1.0f / (denom[i >> 5] + 1e-16f);   // 32 float4 per segment row
    float4 v = out4[i];
    v.x *= rd; v.y *= rd; v.z *= rd; v.w *= rd;
    out4[i] = v;
}

// ---------- launch ----------
extern "C" void kernel_launch(void* const* d_in, const int* in_sizes, int n_in,
                              void* d_out, int out_size, void* d_ws, size_t ws_size,
                              hipStream_t stream) {
    const float* x  = (const float*)d_in[0];
    const int* idx  = (const int*)d_in[1];
    const float* W1 = (const float*)d_in[2];
    const float* b1 = (const float*)d_in[3];
    const float* W2 = (const float*)d_in[4];
    const float* b2 = (const float*)d_in[5];
    const float* Wt = (const float*)d_in[6];
    const float* bt = (const float*)d_in[7];
    float* out = (float*)d_out;

    const int n_nodes = in_sizes[1];          // 1,000,000
    const int nseg = out_size / D;            // 8192
    const int nchunks = (n_nodes + 63) / 64;  // 15625

    // workspace layout
    char* base = (char*)d_ws;
    size_t off = 0;
    float* denom = (float*)(base + off);             off += (size_t)nseg * 4;
    off = (off + 511) & ~511ull;
    __bf16* WtT_hi = (__bf16*)(base + off);          off += (size_t)D * D * 2;
    __bf16* WtT_lo = (__bf16*)(base + off);          off += (size_t)D * D * 2;
    __bf16* W1T_hi = (__bf16*)(base + off);          off += (size_t)DH * D * 2;
    (void)ws_size;

    hipMemsetAsync(d_out, 0, (size_t)out_size * sizeof(float), stream);
    hipLaunchKernelGGL(init_kernel, dim3(64), dim3(256), 0, stream,
                       Wt, W1, denom, WtT_hi, WtT_lo, W1T_hi, nseg);
    hipLaunchKernelGGL(fused_kernel, dim3(2048), dim3(256), 0, stream,
                       x, idx, W1T_hi, b1, W2, b2,
                       WtT_hi, WtT_lo, bt, denom, out, n_nodes, nchunks);
    int n4 = out_size / 4;
    hipLaunchKernelGGL(norm_kernel, dim3((n4 + 255) / 256), dim3(256), 0, stream,
                       (float4*)d_out, denom, n4);
}

// Round 14
// 985.029 us; speedup vs baseline: 1.2576x; 1.2576x over previous
//
#include <hip/hip_runtime.h>
#include <hip/hip_bf16.h>
#include <math.h>

// N=1e6 nodes, D_IN=128, hidden=64, D_OUT=128, SEGS=8192.
#define D   128
#define DH  64

typedef __attribute__((ext_vector_type(8))) __bf16 bf16x8;
typedef __attribute__((ext_vector_type(4))) float  f32x4;

union BF4 { __bf16 b[4]; ushort4 u; };

// split v -> hi + lo (both bf16): hi = rne(v), lo = rne(v - hi)
static __device__ __forceinline__ void bf16_split(float v, __bf16& hi, __bf16& lo) {
    hi = (__bf16)v;
    lo = (__bf16)(v - (float)hi);
}

// ---------- K0: zero denom + transpose/split weights ----------
__global__ void init_kernel(const float* __restrict__ Wt, const float* __restrict__ W1,
                            float* __restrict__ denom,
                            __bf16* __restrict__ WtT_hi, __bf16* __restrict__ WtT_lo,
                            __bf16* __restrict__ W1T_hi, __bf16* __restrict__ W1T_lo,
                            int nseg) {
    int i = blockIdx.x * 256 + threadIdx.x;
    if (i < nseg) denom[i] = 0.0f;
    if (i < D * D) {                      // WtT[j][k] = Wt[k][j]
        int j = i >> 7, k = i & (D - 1);
        __bf16 hi, lo; bf16_split(Wt[k * D + j], hi, lo);
        WtT_hi[j * D + k] = hi; WtT_lo[j * D + k] = lo;
    }
    if (i < DH * D) {                     // W1T[h][k] = W1[k][h]
        int h = i >> 7, k = i & (D - 1);
        __bf16 hi, lo; bf16_split(W1[k * DH + h], hi, lo);
        W1T_hi[h * D + k] = hi; W1T_lo[h * D + k] = lo;
    }
}

// write a staged fp32 chunk (8 float4 regs/thread) as swizzled hi/lo bf16 planes
static __device__ __forceinline__ void write_x_planes(
        const float4* xv, int tid, unsigned char* Ahi, unsigned char* Alo) {
    #pragma unroll
    for (int q = 0; q < 8; ++q) {
        int f = q * 256 + tid;            // float4 id within chunk (2048 total)
        int row = f >> 5, c4 = f & 31;
        BF4 h4, l4;
        bf16_split(xv[q].x, h4.b[0], l4.b[0]);
        bf16_split(xv[q].y, h4.b[1], l4.b[1]);
        bf16_split(xv[q].z, h4.b[2], l4.b[2]);
        bf16_split(xv[q].w, h4.b[3], l4.b[3]);
        int byte = (row * 256 + c4 * 8) ^ ((row & 7) << 4);
        *(ushort4*)(Ahi + byte) = h4.u;
        *(ushort4*)(Alo + byte) = l4.u;
    }
}

static __device__ __forceinline__ void load_x_chunk(
        const float4* __restrict__ xs, int chunk, int n_nodes, int tid, float4* xv) {
    #pragma unroll
    for (int q = 0; q < 8; ++q) {
        int f = q * 256 + tid;
        int node = chunk * 64 + (f >> 5);
        xv[q] = (node < n_nodes) ? xs[(size_t)chunk * 2048 + f]
                                 : make_float4(0.f, 0.f, 0.f, 0.f);
    }
}

// ---------- K1 (fused): gate -> e=exp(gate); denom += e; out += e * relu(x@Wt+bt) ----------
// A planes double-buffered in LDS: ONE barrier per chunk. Stage(c+1) overlaps compute(c);
// epilogue atomics overlap next chunk's MFMA (other waves proceed after the barrier).
// Hazards: buf 2-deep (write p^1 pre-barrier(i), read p^1 post-barrier(i));
// gpart 2-deep (epilogue(i) reads q=i&1; next write to q is iter i+2, post-barrier(i+1));
// segs 3-deep (epilogue(i) reads i%3 concurrent with stage(i+1) writing (i+2)%3).
__global__ __launch_bounds__(256, 2)
void fused_kernel(const float* __restrict__ x, const int* __restrict__ idx,
                  const __bf16* __restrict__ W1T_hi, const __bf16* __restrict__ W1T_lo,
                  const float* __restrict__ b1, const float* __restrict__ W2,
                  const float* __restrict__ b2,
                  const __bf16* __restrict__ WtT_hi, const __bf16* __restrict__ WtT_lo,
                  const float* __restrict__ bt,
                  float* __restrict__ denom, float* __restrict__ out,
                  int n_nodes, int nchunks) {
    __shared__ __align__(16) unsigned char Ahi[2][64 * 256], Alo[2][64 * 256];  // 64 KB
    __shared__ float gpart[2][4][64];                                           // 2 KB
    __shared__ int   segs[3][64];
    int tid = threadIdx.x, lane = tid & 63, w = tid >> 6;
    int g = lane >> 4, l15 = lane & 15;

    // gate B frags: wave w owns hidden cols w*16..w*16+15 (32 VGPR, 3-term split)
    bf16x8 B1h[4], B1l[4];
    {
        const __bf16* ph = W1T_hi + (size_t)(w * 16 + l15) * D;
        const __bf16* pl = W1T_lo + (size_t)(w * 16 + l15) * D;
        #pragma unroll
        for (int kk = 0; kk < 4; ++kk) {
            B1h[kk] = *(const bf16x8*)(ph + kk * 32 + g * 8);
            B1l[kk] = *(const bf16x8*)(pl + kk * 32 + g * 8);
        }
    }
    // transform B frags: wave w owns out cols (2w..2w+1)*16 (64 VGPR)
    bf16x8 Bth[2][4], Btl[2][4];
    #pragma unroll
    for (int nt = 0; nt < 2; ++nt) {
        const __bf16* ph = WtT_hi + (size_t)((2 * w + nt) * 16 + l15) * D;
        const __bf16* pl = WtT_lo + (size_t)((2 * w + nt) * 16 + l15) * D;
        #pragma unroll
        for (int kk = 0; kk < 4; ++kk) {
            Bth[nt][kk] = *(const bf16x8*)(ph + kk * 32 + g * 8);
            Btl[nt][kk] = *(const bf16x8*)(pl + kk * 32 + g * 8);
        }
    }
    float b1v = b1[w * 16 + l15], w2v = W2[w * 16 + l15], b2v = b2[0];
    float btv[2] = { bt[(2 * w + 0) * 16 + l15], bt[(2 * w + 1) * 16 + l15] };
    const float4* xs = (const float4*)x;

    // prologue: stage chunk c0 into buf0 + segs[0]
    {
        int c0 = blockIdx.x;
        if (c0 < nchunks) {
            float4 xv[8];
            load_x_chunk(xs, c0, n_nodes, tid, xv);
            write_x_planes(xv, tid, Ahi[0], Alo[0]);
            if (tid < 64) {
                int node = c0 * 64 + tid;
                segs[0][tid] = (node < n_nodes) ? idx[node] : 0;
            }
        }
    }
    __syncthreads();                            // publish c0

    int it = 0;
    for (int c = blockIdx.x; c < nchunks; c += gridDim.x, ++it) {
        int p = it & 1, sq = it % 3, sq1 = (it + 1) % 3;
        int cn = c + gridDim.x;
        float4 xn[8]; int sgn = 0;
        if (cn < nchunks) {
            load_x_chunk(xs, cn, n_nodes, tid, xn);        // prefetch: issue early
            if (tid < 64) {
                int node = cn * 64 + tid;
                sgn = (node < n_nodes) ? idx[node] : 0;
            }
        }

        // ---- merged GEMM: one A-fragment read feeds gate (3 MFMA) + transform (6 MFMA) ----
        f32x4 gacc[4];
        f32x4 acc[4][2];
        #pragma unroll
        for (int rt = 0; rt < 4; ++rt) {
            gacc[rt] = (f32x4){0.f, 0.f, 0.f, 0.f};
            #pragma unroll
            for (int nt = 0; nt < 2; ++nt) acc[rt][nt] = (f32x4){0.f, 0.f, 0.f, 0.f};
        }
        #pragma unroll
        for (int kk = 0; kk < 4; ++kk) {
            #pragma unroll
            for (int rt = 0; rt < 4; ++rt) {
                int arow = rt * 16 + l15;
                int ab = (arow * 256 + kk * 64 + g * 16) ^ ((arow & 7) << 4);
                bf16x8 ah = *(const bf16x8*)(Ahi[p] + ab);
                bf16x8 al = *(const bf16x8*)(Alo[p] + ab);
                gacc[rt] = __builtin_amdgcn_mfma_f32_16x16x32_bf16(ah, B1h[kk], gacc[rt], 0, 0, 0);
                gacc[rt] = __builtin_amdgcn_mfma_f32_16x16x32_bf16(ah, B1l[kk], gacc[rt], 0, 0, 0);
                gacc[rt] = __builtin_amdgcn_mfma_f32_16x16x32_bf16(al, B1h[kk], gacc[rt], 0, 0, 0);
                #pragma unroll
                for (int nt = 0; nt < 2; ++nt) {
                    acc[rt][nt] = __builtin_amdgcn_mfma_f32_16x16x32_bf16(ah, Bth[nt][kk], acc[rt][nt], 0, 0, 0);
                    acc[rt][nt] = __builtin_amdgcn_mfma_f32_16x16x32_bf16(ah, Btl[nt][kk], acc[rt][nt], 0, 0, 0);
                    acc[rt][nt] = __builtin_amdgcn_mfma_f32_16x16x32_bf16(al, Bth[nt][kk], acc[rt][nt], 0, 0, 0);
                }
            }
        }

        // ---- gate partial reduce over this wave's 16 hidden cols -> gpart[it&1] ----
        #pragma unroll
        for (int rt = 0; rt < 4; ++rt) {
            #pragma unroll
            for (int r = 0; r < 4; ++r) {
                float pv = fmaxf(gacc[rt][r] + b1v, 0.f) * w2v;
                pv += __shfl_xor(pv, 1);
                pv += __shfl_xor(pv, 2);
                pv += __shfl_xor(pv, 4);
                pv += __shfl_xor(pv, 8);
                if (l15 == 0) gpart[p][w][rt * 16 + g * 4 + r] = pv;
            }
        }

        // ---- stage next chunk into the other buffer (overlaps nothing being read) ----
        if (cn < nchunks) {
            write_x_planes(xn, tid, Ahi[p ^ 1], Alo[p ^ 1]);
            if (tid < 64) segs[sq1][tid] = sgn;
        }
        __syncthreads();        // publish gpart[p], buf[p^1], segs[sq1]; buf[p] reads done

        // ---- e per lane (every wave, redundant) ----
        float gt = gpart[p][0][lane] + gpart[p][1][lane] + gpart[p][2][lane]
                 + gpart[p][3][lane] + b2v;
        int node0 = c * 64 + lane;
        float e = (node0 < n_nodes) ? __expf(gt) : 0.f;

        // ---- wave0: denom atomics (concurrent with other waves' epilogues) ----
        if (w == 0) {
            int ga = lane >> 4;
            int sa = segs[sq][ga * 16], sb = segs[sq][ga * 16 + 15];
            if (sa == sb) {
                float v = e;
                v += __shfl_xor(v, 1);
                v += __shfl_xor(v, 2);
                v += __shfl_xor(v, 4);
                v += __shfl_xor(v, 8);
                if ((lane & 15) == 0) atomicAdd(denom + sa, v);
            } else {
                atomicAdd(denom + segs[sq][lane], e);
            }
        }

        // ---- scatter epilogue: out += e * relu(t + bt), segmented column sums ----
        int s0 = segs[sq][0], s63 = segs[sq][63];
        if (s0 == s63) {                        // whole chunk one segment
            float s[2] = {0.f, 0.f};
            #pragma unroll
            for (int rt = 0; rt < 4; ++rt)
                #pragma unroll
                for (int r = 0; r < 4; ++r) {
                    float a = __shfl(e, rt * 16 + g * 4 + r);
                    s[0] += a * fmaxf(acc[rt][0][r] + btv[0], 0.f);
                    s[1] += a * fmaxf(acc[rt][1][r] + btv[1], 0.f);
                }
            s[0] += __shfl_xor(s[0], 16); s[0] += __shfl_xor(s[0], 32);
            s[1] += __shfl_xor(s[1], 16); s[1] += __shfl_xor(s[1], 32);
            if (g == 0)      atomicAdd(&out[(size_t)s0 * D + (2 * w + 0) * 16 + l15], s[0]);
            else if (g == 1) atomicAdd(&out[(size_t)s0 * D + (2 * w + 1) * 16 + l15], s[1]);
        } else {
            #pragma unroll
            for (int rt = 0; rt < 4; ++rt) {
                int sa = segs[sq][rt * 16], sb = segs[sq][rt * 16 + 15];
                if (sa == sb) {                 // 16-row tile uniform
                    float s[2] = {0.f, 0.f};
                    #pragma unroll
                    for (int r = 0; r < 4; ++r) {
                        float a = __shfl(e, rt * 16 + g * 4 + r);
                        s[0] += a * fmaxf(acc[rt][0][r] + btv[0], 0.f);
                        s[1] += a * fmaxf(acc[rt][1][r] + btv[1], 0.f);
                    }
                    s[0] += __shfl_xor(s[0], 16); s[0] += __shfl_xor(s[0], 32);
                    s[1] += __shfl_xor(s[1], 16); s[1] += __shfl_xor(s[1], 32);
                    if (g == 0)      atomicAdd(&out[(size_t)sa * D + (2 * w + 0) * 16 + l15], s[0]);
                    else if (g == 1) atomicAdd(&out[(size_t)sa * D + (2 * w + 1) * 16 + l15], s[1]);
                } else {                        // boundary inside tile: per-row atomics
                    #pragma unroll
                    for (int r = 0; r < 4; ++r) {
                        int row = rt * 16 + g * 4 + r;
                        int sg = segs[sq][row];
                        float a = __shfl(e, row);
                        atomicAdd(&out[(size_t)sg * D + (2 * w + 0) * 16 + l15],
                                  a * fmaxf(acc[rt][0][r] + btv[0], 0.f));
                        atomicAdd(&out[(size_t)sg * D + (2 * w + 1) * 16 + l15],
                                  a * fmaxf(acc[rt][1][r] + btv[1], 0.f));
                    }
                }
            }
        }
    }
}

// ---------- K2: out[s][:] /= (denom[s] + eps) ----------
__global__ void norm_kernel(float4* __restrict__ out4, const float* __restrict__ denom,
                            int n4) {
    int i = blockIdx.x * 256 + threadIdx.x;
    if (i >= n4) return;
    float rd = 1.0f / (denom[i >> 5] + 1e-16f);   // 32 float4 per segment row
    float4 v = out4[i];
    v.x *= rd; v.y *= rd; v.z *= rd; v.w *= rd;
    out4[i] = v;
}

// ---------- launch ----------
extern "C" void kernel_launch(void* const* d_in, const int* in_sizes, int n_in,
                              void* d_out, int out_size, void* d_ws, size_t ws_size,
                              hipStream_t stream) {
    const float* x  = (const float*)d_in[0];
    const int* idx  = (const int*)d_in[1];
    const float* W1 = (const float*)d_in[2];
    const float* b1 = (const float*)d_in[3];
    const float* W2 = (const float*)d_in[4];
    const float* b2 = (const float*)d_in[5];
    const float* Wt = (const float*)d_in[6];
    const float* bt = (const float*)d_in[7];
    float* out = (float*)d_out;

    const int n_nodes = in_sizes[1];          // 1,000,000
    const int nseg = out_size / D;            // 8192
    const int nchunks = (n_nodes + 63) / 64;  // 15625

    // workspace layout
    char* base = (char*)d_ws;
    size_t off = 0;
    float* denom = (float*)(base + off);             off += (size_t)nseg * 4;
    off = (off + 511) & ~511ull;
    __bf16* WtT_hi = (__bf16*)(base + off);          off += (size_t)D * D * 2;
    __bf16* WtT_lo = (__bf16*)(base + off);          off += (size_t)D * D * 2;
    __bf16* W1T_hi = (__bf16*)(base + off);          off += (size_t)DH * D * 2;
    __bf16* W1T_lo = (__bf16*)(base + off);          off += (size_t)DH * D * 2;
    (void)ws_size;

    hipMemsetAsync(d_out, 0, (size_t)out_size * sizeof(float), stream);
    hipLaunchKernelGGL(init_kernel, dim3(64), dim3(256), 0, stream,
                       Wt, W1, denom, WtT_hi, WtT_lo, W1T_hi, W1T_lo, nseg);
    hipLaunchKernelGGL(fused_kernel, dim3(2048), dim3(256), 0, stream,
                       x, idx, W1T_hi, W1T_lo, b1, W2, b2,
                       WtT_hi, WtT_lo, bt, denom, out, n_nodes, nchunks);
    int n4 = out_size / 4;
    hipLaunchKernelGGL(norm_kernel, dim3((n4 + 255) / 256), dim3(256), 0, stream,
                       (float4*)d_out, denom, n4);
}